// Round 5
// baseline (691.610 us; speedup 1.0000x reference)
//
#include <hip/hip_runtime.h>
#include <hip/hip_bf16.h>
#include <stdint.h>

#define BATCH   16384
#define EXPERTS 8
#define IN_DIM  1024
#define OUT_DIM 1024

typedef unsigned short u16;
typedef short  bf16x8 __attribute__((ext_vector_type(8)));
typedef float  f32x4  __attribute__((ext_vector_type(4)));

__device__ __forceinline__ u16 f2bf(float f) {
  uint32_t u = __float_as_uint(f);
  u += 0x7fffu + ((u >> 16) & 1u);   // round-to-nearest-even
  return (u16)(u >> 16);
}

// async global->LDS, 16B per lane, wave-uniform LDS base + lane*16
#define GLDS16(g, l)                                                      \
  __builtin_amdgcn_global_load_lds(                                       \
      (const __attribute__((address_space(1))) void*)(g),                 \
      (__attribute__((address_space(3))) void*)(l), 16, 0, 0)

#define MFMA_BF16 __builtin_amdgcn_mfma_f32_16x16x32_bf16

// ---------------- kernel 1: x fp32 -> bf16 ----------------
__global__ void cvt_x(const float* __restrict__ x, u16* __restrict__ xb) {
  size_t i = ((size_t)blockIdx.x * 256 + threadIdx.x) * 4;
  float4 v = *reinterpret_cast<const float4*>(x + i);
  ushort4 o;
  o.x = f2bf(v.x); o.y = f2bf(v.y); o.z = f2bf(v.z); o.w = f2bf(v.w);
  *reinterpret_cast<ushort4*>(xb + i) = o;
}

// ------- kernel 2: W[e][i][o] fp32 -> Wbt[e][o][i] bf16 (transpose) -------
__global__ void cvt_w(const float* __restrict__ W, u16* __restrict__ wbt) {
  __shared__ u16 t[64][72];            // +8 pad
  const int e  = blockIdx.z;
  const int i0 = blockIdx.x * 64;
  const int o0 = blockIdx.y * 64;
  const int tid = threadIdx.x;
  const int c  = (tid & 15) * 4;
  const int r_ = tid >> 4;
  const float* src = W + ((size_t)e << 20);
#pragma unroll
  for (int p = 0; p < 4; ++p) {
    int r = r_ + p * 16;               // i-row
    float4 v = *reinterpret_cast<const float4*>(src + (size_t)(i0 + r) * 1024 + o0 + c);
    t[r][c + 0] = f2bf(v.x); t[r][c + 1] = f2bf(v.y);
    t[r][c + 2] = f2bf(v.z); t[r][c + 3] = f2bf(v.w);
  }
  __syncthreads();
  u16* dst = wbt + ((size_t)e << 20);
#pragma unroll
  for (int p = 0; p < 4; ++p) {
    int orow = r_ + p * 16;            // o-row
    ushort4 u;
    u.x = t[c + 0][orow]; u.y = t[c + 1][orow];
    u.z = t[c + 2][orow]; u.w = t[c + 3][orow];
    *reinterpret_cast<ushort4*>(dst + (size_t)(o0 + orow) * 1024 + i0 + c) = u;
  }
}

// ---------------- kernel 3: fused expert GEMM, K-outer / expert-inner ----
// BM=256 BN=128 BK=64, 512 thr = 8 waves (2M x 4N), wave -> 128x32 out.
// A staged once per K-tile; a-frags in regs across all 8 expert phases.
// Per phase: ALL LDS reads at TOP (latency hides under barrier wait), then
// stage (distance-3, 4 B-buffers, buf = E&3 compile-time), counted vmcnt,
// barrier, lgkmcnt(0)+sched_barrier, pure-reg 32-MFMA + fold cluster, barrier.
// Ledger: c={3,3,3,3,2,2,2,2}; VM(g)=c(g)+c(g-1) -> stages <=g-2 drained at
// phase g's vmcnt, published by its barrier, first read at phase g+1 top.
//
// LDS (u16 elems): A dbuf @0,@16384 (32KB ea); B bufs @32768+i*8192 (16KB ea,
// i=0..3); wl f32[8][256] @65536 (8KB). Total 69632 elems = 136KB.
__global__ __launch_bounds__(512, 2)
void moe_gemm(const u16* __restrict__ xb, const u16* __restrict__ wbt,
              const float* __restrict__ wts, const float* __restrict__ bias,
              float* __restrict__ y) {
  __shared__ u16 sm[69632];
  const char* smb = (const char*)sm;
  float* wl = (float*)(sm + 65536);

  const int tid = threadIdx.x;
  const int l   = tid & 63;
  const int w   = tid >> 6;            // wave 0..7
  const int wm  = w >> 2;              // 0..1  (M half)
  const int wn  = w & 3;               // 0..3  (N quarter)
  const int n0  = (blockIdx.x & 7) * 128;   // XCD-affine B-panel
  const int b0  = (blockIdx.x >> 3) * 256;

  // ---- stage expert weights wl[e][256] for this block's rows (ds_write)
#pragma unroll
  for (int i = 0; i < 4; ++i) {
    const int flat = tid + i * 512;
    const int ee = flat & 7, r = flat >> 3;
    wl[ee * 256 + r] = wts[(size_t)(b0 + r) * EXPERTS + ee];
  }

  // ---- staging geometry (pre-swizzled global source, linear GLDS dest)
  const int rb    = (w << 3) + (l >> 3);              // 0..63
  const int chunk = ((l & 7) ^ (l >> 3)) << 3;        // swizzled k-chunk (elems)
  const u16* pAg = xb  + (size_t)(b0 + rb) * IN_DIM + chunk;
  const u16* pBg = wbt + (size_t)(n0 + rb) * IN_DIM + chunk;

  // ---- fragment read byte-offsets
  const int lane15 = l & 15;
  const int swzb  = (((l >> 4) << 4)) ^ ((l & 7) << 4);
  const int aoffb = (wm << 14) + lane15 * 128 + swzb;   // within A buf (bytes)
  const int boffb = lane15 * 128 + swzb + (wn << 12);   // within B buf (bytes)
  const int wlo   = (wm << 9) + ((l >> 4) << 4);        // wl byte off per m

  f32x4 accY[8][2];
#pragma unroll
  for (int m = 0; m < 8; ++m)
#pragma unroll
    for (int n = 0; n < 2; ++n) accY[m][n] = (f32x4){0.f, 0.f, 0.f, 0.f};
  const f32x4 fz = (f32x4){0.f, 0.f, 0.f, 0.f};

  bf16x8 a[8][2];

  // ---- prologue: A(tile0)x4 -> Abuf0; B e0/e1/e2 pairs -> bufB0/1/2
#pragma unroll
  for (int q = 0; q < 4; ++q)
    GLDS16(pAg + (size_t)q * 65536, sm + q * 4096 + (w << 9));
  GLDS16(pBg,                    sm + 32768 + (w << 9));
  GLDS16(pBg + 65536,            sm + 32768 + 4096 + (w << 9));
  GLDS16(pBg + 1048576,          sm + 40960 + (w << 9));
  GLDS16(pBg + 1048576 + 65536,  sm + 40960 + 4096 + (w << 9));
  GLDS16(pBg + 2097152,          sm + 49152 + (w << 9));
  GLDS16(pBg + 2097152 + 65536,  sm + 49152 + 4096 + (w << 9));
  asm volatile("s_waitcnt vmcnt(4)" ::: "memory");    // A0 + B-e0 complete
  asm volatile("s_waitcnt lgkmcnt(0)" ::: "memory");  // wl ds_writes drained
  __builtin_amdgcn_s_barrier();

// B read base (bytes) and stage target (elems) — compile-time per E.
#define BRD(E) (65536 + ((E) & 3) * 16384)
#define BST(E) (32768 + (((E) + 3) & 3) * 8192)

#define PHASE(E, VM)                                                       \
  {                                                                        \
    /* ---- top: ALL LDS reads for THIS phase (latency hides at barrier) */\
    if ((E) == 0) {                                                        \
      _Pragma("unroll")                                                    \
      for (int m = 0; m < 8; ++m) {                                        \
        a[m][0] = *(const bf16x8*)(smb + (arB + aoffb + m * 2048));        \
        a[m][1] = *(const bf16x8*)(smb + ((arB + aoffb + m * 2048) ^ 64)); \
      }                                                                    \
    }                                                                      \
    bf16x8 bc[2][2];                                                       \
    _Pragma("unroll")                                                      \
    for (int n = 0; n < 2; ++n) {                                          \
      bc[n][0] = *(const bf16x8*)(smb + (BRD(E) + boffb + n * 2048));      \
      bc[n][1] = *(const bf16x8*)(smb + ((BRD(E) + boffb + n * 2048) ^ 64)); \
    }                                                                      \
    f32x4 wv[8];                                                           \
    _Pragma("unroll")                                                      \
    for (int m = 0; m < 8; ++m)                                            \
      wv[m] = *(const f32x4*)(smb + 131072 + (E) * 1024 + wlo + m * 64);   \
    /* ---- stage for phase g+3 (distance 3) */                            \
    {                                                                      \
      const int et = ((E) + 3) & 7;                                        \
      const int kt = ((E) <= 4) ? kk : kn;                                 \
      const u16* srcB = pBg + (size_t)et * 1048576 + (size_t)kt * 64;      \
      GLDS16(srcB,         sm + BST(E) + (w << 9));                        \
      GLDS16(srcB + 65536, sm + BST(E) + 4096 + (w << 9));                 \
    }                                                                      \
    if ((E) < 4)                                                           \
      GLDS16(pAg + (size_t)(E) * 65536 + (size_t)kn * 64,                  \
             sm + awE + (E) * 4096 + (w << 9));                            \
    asm volatile("s_waitcnt vmcnt(" #VM ")" ::: "memory");                 \
    __builtin_amdgcn_s_barrier();                                          \
    asm volatile("s_waitcnt lgkmcnt(0)" ::: "memory");                     \
    __builtin_amdgcn_sched_barrier(0);                                     \
    __builtin_amdgcn_s_setprio(1);                                         \
    _Pragma("unroll")                                                      \
    for (int m = 0; m < 8; ++m) {                                          \
      _Pragma("unroll")                                                    \
      for (int n = 0; n < 2; ++n) {                                        \
        f32x4 t = MFMA_BF16(a[m][0], bc[n][0], fz, 0, 0, 0);               \
        t = MFMA_BF16(a[m][1], bc[n][1], t, 0, 0, 0);                      \
        accY[m][n] += wv[m] * t;                                           \
      }                                                                    \
    }                                                                      \
    __builtin_amdgcn_s_setprio(0);                                         \
    __builtin_amdgcn_s_barrier();                                          \
  }

#pragma unroll 1
  for (int kk = 0; kk < 16; ++kk) {
    const int kn  = (kk + 1) & 15;
    const int arB = (kk & 1) << 15;    // A read base (bytes)
    const int awE = (kn & 1) << 14;    // A stage base (elems)
    PHASE(0, 5)
    PHASE(1, 6)
    PHASE(2, 6)
    PHASE(3, 6)
    PHASE(4, 5)
    PHASE(5, 4)
    PHASE(6, 4)
    PHASE(7, 4)
  }
  asm volatile("s_waitcnt vmcnt(0)" ::: "memory");   // drain wrap-around stages

  // ---- epilogue: bias term + store fp32
  float bv[2][8];
#pragma unroll
  for (int n = 0; n < 2; ++n) {
    const int c = n0 + (wn << 5) + (n << 4) + lane15;
#pragma unroll
    for (int ee = 0; ee < 8; ++ee) bv[n][ee] = bias[ee * OUT_DIM + c];
  }
#pragma unroll
  for (int m = 0; m < 8; ++m) {
    const int wrow = (wm << 7) + (m << 4) + ((l >> 4) << 2);
    f32x4 wv[8];
#pragma unroll
    for (int ee = 0; ee < 8; ++ee) wv[ee] = *(const f32x4*)(wl + ee * 256 + wrow);
#pragma unroll
    for (int n = 0; n < 2; ++n) {
      const int c = n0 + (wn << 5) + (n << 4) + lane15;
#pragma unroll
      for (int j = 0; j < 4; ++j) {
        float v = accY[m][n][j];
#pragma unroll
        for (int ee = 0; ee < 8; ++ee) v += wv[ee][j] * bv[n][ee];
        y[(size_t)(b0 + wrow + j) * OUT_DIM + c] = v;
      }
    }
  }
}

extern "C" void kernel_launch(void* const* d_in, const int* in_sizes, int n_in,
                              void* d_out, int out_size, void* d_ws, size_t ws_size,
                              hipStream_t stream) {
  const float* x    = (const float*)d_in[0];
  const float* wts  = (const float*)d_in[1];
  const float* W    = (const float*)d_in[2];
  const float* bias = (const float*)d_in[3];
  float* y = (float*)d_out;

  const size_t xb_elems = (size_t)BATCH * IN_DIM;                 // 32 MB bf16
  const size_t wb_elems = (size_t)EXPERTS * IN_DIM * OUT_DIM;     // 16 MB bf16
  if (ws_size < (xb_elems + wb_elems) * sizeof(u16)) return;      // loud failure
  u16* xb  = (u16*)d_ws;
  u16* wbt = xb + xb_elems;

  cvt_x<<<(BATCH * IN_DIM) / (4 * 256), 256, 0, stream>>>(x, xb);
  cvt_w<<<dim3(IN_DIM / 64, OUT_DIM / 64, EXPERTS), 256, 0, stream>>>(W, wbt);
  moe_gemm<<<dim3((BATCH / 256) * (OUT_DIM / 128)), 512, 0, stream>>>(xb, wbt, wts, bias, y);
}

// Round 6
// 353.408 us; speedup vs baseline: 1.9570x; 1.9570x over previous
//
#include <hip/hip_runtime.h>
#include <hip/hip_bf16.h>
#include <stdint.h>

#define BATCH   16384
#define EXPERTS 8
#define IN_DIM  1024
#define OUT_DIM 1024
#define KS      8256          // 8192 + 64 (8 bias cols + 56 zeros) = 129*64
#define NT      129

typedef unsigned short u16;
typedef short  bf16x8 __attribute__((ext_vector_type(8)));
typedef float  f32x4  __attribute__((ext_vector_type(4)));

__device__ __forceinline__ u16 f2bf(float f) {
  uint32_t u = __float_as_uint(f);
  u += 0x7fffu + ((u >> 16) & 1u);   // RNE
  return (u16)(u >> 16);
}

#define GLDS16(g, l)                                                      \
  __builtin_amdgcn_global_load_lds(                                       \
      (const __attribute__((address_space(1))) void*)(g),                 \
      (__attribute__((address_space(3))) void*)(l), 16, 0, 0)

#define MFMA_BF16 __builtin_amdgcn_mfma_f32_16x16x32_bf16

// ============ Z path: y = Zb @ Wt^T, Z[b][e*1024+i] = w[b,e]*x[b,i] =======

// build_z: one block per batch row; writes all KS cols (incl. bias tail).
__global__ void build_z(const float* __restrict__ x, const float* __restrict__ wts,
                        u16* __restrict__ Zb) {
  const int b = blockIdx.x;
  const int t = threadIdx.x;
  float w8[8];
#pragma unroll
  for (int e = 0; e < 8; ++e) w8[e] = wts[(size_t)b * 8 + e];   // wave-uniform
  float4 xv = *reinterpret_cast<const float4*>(x + (size_t)b * 1024 + t * 4);
  u16* zr = Zb + (size_t)b * KS;
#pragma unroll
  for (int e = 0; e < 8; ++e) {
    ushort4 o;
    o.x = f2bf(w8[e] * xv.x); o.y = f2bf(w8[e] * xv.y);
    o.z = f2bf(w8[e] * xv.z); o.w = f2bf(w8[e] * xv.w);
    *reinterpret_cast<ushort4*>(zr + e * 1024 + t * 4) = o;
  }
  if (t < 16) {             // tail cols 8192..8255: first 8 = w[b,e], rest 0
    ushort4 o; u16 v[4];
#pragma unroll
    for (int i = 0; i < 4; ++i) {
      int c = t * 4 + i;
      v[i] = (c < 8) ? f2bf(w8[c]) : (u16)0;
    }
    o.x = v[0]; o.y = v[1]; o.z = v[2]; o.w = v[3];
    *reinterpret_cast<ushort4*>(zr + 8192 + t * 4) = o;
  }
}

// build_wt: W[e][i][o] f32 -> Wt[o][e*1024+i] bf16 (stride KS)
__global__ void build_wt(const float* __restrict__ W, u16* __restrict__ wt) {
  __shared__ u16 tb[64][72];
  const int e  = blockIdx.z;
  const int i0 = blockIdx.x * 64;
  const int o0 = blockIdx.y * 64;
  const int tid = threadIdx.x;
  const int c  = (tid & 15) * 4;
  const int r_ = tid >> 4;
  const float* src = W + ((size_t)e << 20);
#pragma unroll
  for (int p = 0; p < 4; ++p) {
    int r = r_ + p * 16;
    float4 v = *reinterpret_cast<const float4*>(src + (size_t)(i0 + r) * 1024 + o0 + c);
    tb[r][c + 0] = f2bf(v.x); tb[r][c + 1] = f2bf(v.y);
    tb[r][c + 2] = f2bf(v.z); tb[r][c + 3] = f2bf(v.w);
  }
  __syncthreads();
#pragma unroll
  for (int p = 0; p < 4; ++p) {
    int orow = r_ + p * 16;
    ushort4 u;
    u.x = tb[c + 0][orow]; u.y = tb[c + 1][orow];
    u.z = tb[c + 2][orow]; u.w = tb[c + 3][orow];
    *reinterpret_cast<ushort4*>(wt + (size_t)(o0 + orow) * KS + e * 1024 + i0 + c) = u;
  }
}

// bias_tail: Wt[o][8192+c] = c<8 ? bias[c][o] : 0
__global__ void bias_tail(const float* __restrict__ bias, u16* __restrict__ wt) {
  const int o = blockIdx.x * 256 + threadIdx.x;
  u16* row = wt + (size_t)o * KS + 8192;
#pragma unroll
  for (int c = 0; c < 64; ++c)
    row[c] = (c < 8) ? f2bf(bias[(size_t)c * OUT_DIM + o]) : (u16)0;
}

// zgemm: BM=256 BN=128 BK=64, 512 thr = 8 waves (2M x 4N), wave 128x32.
// Uniform schedule: 2 phases per K-tile (kf halves). Per phase:
//   top: 10 ds_read_b128 (a:8, b:2) of CURRENT tile (buf published last phase)
//   stage: 3 GLDS of tile t+2 into 3rd buf (A0,A1,B0 | A2,A3,B1)
//   vmcnt(6)  [uniform ledger: drains tile t+1's older half]
//   barrier; lgkmcnt(0); sched_barrier; setprio(1); 16 MFMA; setprio(0); barrier
// Triple-buffered A (3x32KB) and B (3x16KB): LDS 144KB.
__global__ __launch_bounds__(512, 2)
void zgemm(const u16* __restrict__ Z, const u16* __restrict__ Wt,
           float* __restrict__ y) {
  __shared__ u16 sm[73728];          // A: 3x16384 elems @0; B: 3x8192 @49152
  const char* smb = (const char*)sm;
  const int tid = threadIdx.x;
  const int l   = tid & 63;
  const int w   = tid >> 6;
  const int wm  = w >> 2;            // 0..1
  const int wn  = w & 3;             // 0..3
  const int xcd = blockIdx.x & 7, jj = blockIdx.x >> 3;
  const int b0  = (((xcd << 3) + (jj >> 3)) << 8);   // row-panel*256 (XCD-grouped)
  const int n0  = (jj & 7) * 128;

  const int rb    = (w << 3) + (l >> 3);             // 0..63
  const int chunk = ((l & 7) ^ (l >> 3)) << 3;       // pre-swizzled k-chunk
  const u16* pAg = Z  + (size_t)(b0 + rb) * KS + chunk;
  const u16* pBg = Wt + (size_t)(n0 + rb) * KS + chunk;

  const int lane15 = l & 15;
  const int rswz  = (lane15 & 7) << 4;
  const int k0    = (((l >> 4) << 4)) ^ rswz;        // kf0 byte key (kf1 = ^64)
  const int arow0 = (wm * 128 + lane15) * 128;       // + m*2048
  const int brow0 = (wn * 32 + lane15) * 128;        // + n*2048

  f32x4 acc[8][2];
#pragma unroll
  for (int m = 0; m < 8; ++m)
#pragma unroll
    for (int n = 0; n < 2; ++n) acc[m][n] = (f32x4){0.f, 0.f, 0.f, 0.f};

#define STG_A(q, baseE, kt) GLDS16(pAg + (size_t)((q) * 64) * KS + (size_t)(kt) * 64, \
                                   sm + (baseE) + (q) * 4096 + (w << 9))
#define STG_B(q, baseE, kt) GLDS16(pBg + (size_t)((q) * 64) * KS + (size_t)(kt) * 64, \
                                   sm + (baseE) + (q) * 4096 + (w << 9))

  // prologue: tile0 -> buf0, tile1 -> buf1 (6 calls each); vmcnt(6) leaves tile1
  STG_A(0, 0, 0); STG_A(1, 0, 0); STG_A(2, 0, 0); STG_A(3, 0, 0);
  STG_B(0, 49152, 0); STG_B(1, 49152, 0);
  STG_A(0, 16384, 1); STG_A(1, 16384, 1); STG_A(2, 16384, 1); STG_A(3, 16384, 1);
  STG_B(0, 57344, 1); STG_B(1, 57344, 1);
  asm volatile("s_waitcnt vmcnt(6)" ::: "memory");
  __builtin_amdgcn_s_barrier();

  int aR = 0, aM = 16384, aS = 32768;       // A buf elem bases (read/mid/stage)
  int bR = 49152, bM = 57344, bS = 65536;   // B buf elem bases

#define PH(KKEY, S0, S1, S2)                                               \
  {                                                                        \
    bf16x8 av[8], bv[2];                                                   \
    const int aBase = (aR << 1), bBase = (bR << 1);                        \
    _Pragma("unroll")                                                      \
    for (int m = 0; m < 8; ++m)                                            \
      av[m] = *(const bf16x8*)(smb + aBase + arow0 + m * 2048 + (KKEY));   \
    _Pragma("unroll")                                                      \
    for (int n = 0; n < 2; ++n)                                            \
      bv[n] = *(const bf16x8*)(smb + bBase + brow0 + n * 2048 + (KKEY));   \
    S0; S1; S2;                                                            \
    asm volatile("s_waitcnt vmcnt(6)" ::: "memory");                       \
    __builtin_amdgcn_s_barrier();                                          \
    asm volatile("s_waitcnt lgkmcnt(0)" ::: "memory");                     \
    __builtin_amdgcn_sched_barrier(0);                                     \
    __builtin_amdgcn_s_setprio(1);                                         \
    _Pragma("unroll")                                                      \
    for (int m = 0; m < 8; ++m)                                            \
      _Pragma("unroll")                                                    \
      for (int n = 0; n < 2; ++n)                                          \
        acc[m][n] = MFMA_BF16(av[m], bv[n], acc[m][n], 0, 0, 0);           \
    __builtin_amdgcn_s_setprio(0);                                         \
    __builtin_amdgcn_s_barrier();                                          \
  }

#pragma unroll 1
  for (int t = 0; t < NT; ++t) {
    const int kt2 = t + 2;   // staged tiles 130/131 read in-bounds garbage (pad)
    PH(k0,        STG_A(0, aS, kt2), STG_A(1, aS, kt2), STG_B(0, bS, kt2))
    PH(k0 ^ 64,   STG_A(2, aS, kt2), STG_A(3, aS, kt2), STG_B(1, bS, kt2))
    { int tm = aR; aR = aM; aM = aS; aS = tm; }
    { int tm = bR; bR = bM; bM = bS; bS = tm; }
  }
  asm volatile("s_waitcnt vmcnt(0)" ::: "memory");

  // epilogue: store fp32
#pragma unroll
  for (int m = 0; m < 8; ++m) {
    const int r0 = b0 + wm * 128 + m * 16 + ((l >> 4) << 2);
#pragma unroll
    for (int n = 0; n < 2; ++n) {
      const int c = n0 + wn * 32 + n * 16 + lane15;
#pragma unroll
      for (int j = 0; j < 4; ++j)
        y[(size_t)(r0 + j) * OUT_DIM + c] = acc[m][n][j];
    }
  }
}

// ===================== fallback path (r1, proven) =========================
__global__ void cvt_x(const float* __restrict__ x, u16* __restrict__ xb) {
  size_t i = ((size_t)blockIdx.x * 256 + threadIdx.x) * 4;
  float4 v = *reinterpret_cast<const float4*>(x + i);
  ushort4 o;
  o.x = f2bf(v.x); o.y = f2bf(v.y); o.z = f2bf(v.z); o.w = f2bf(v.w);
  *reinterpret_cast<ushort4*>(xb + i) = o;
}

__global__ void cvt_w(const float* __restrict__ W, u16* __restrict__ wbt) {
  __shared__ u16 t[64][72];
  const int e  = blockIdx.z;
  const int i0 = blockIdx.x * 64;
  const int o0 = blockIdx.y * 64;
  const int tid = threadIdx.x;
  const int c  = (tid & 15) * 4;
  const int r_ = tid >> 4;
  const float* src = W + ((size_t)e << 20);
#pragma unroll
  for (int p = 0; p < 4; ++p) {
    int r = r_ + p * 16;
    float4 v = *reinterpret_cast<const float4*>(src + (size_t)(i0 + r) * 1024 + o0 + c);
    t[r][c + 0] = f2bf(v.x); t[r][c + 1] = f2bf(v.y);
    t[r][c + 2] = f2bf(v.z); t[r][c + 3] = f2bf(v.w);
  }
  __syncthreads();
  u16* dst = wbt + ((size_t)e << 20);
#pragma unroll
  for (int p = 0; p < 4; ++p) {
    int orow = r_ + p * 16;
    ushort4 u;
    u.x = t[c + 0][orow]; u.y = t[c + 1][orow];
    u.z = t[c + 2][orow]; u.w = t[c + 3][orow];
    *reinterpret_cast<ushort4*>(dst + (size_t)(o0 + orow) * 1024 + i0 + c) = u;
  }
}

__global__ __launch_bounds__(256, 4)
void moe_gemm(const u16* __restrict__ xb, const u16* __restrict__ wbt,
              const float* __restrict__ wts, const float* __restrict__ bias,
              float* __restrict__ y) {
  __shared__ u16 As[128 * 64];
  __shared__ u16 Bs[64 * 64];
  const int tid = threadIdx.x;
  const int l   = tid & 63;
  const int w   = tid >> 6;
  const int b0  = blockIdx.x * 128;
  const int n0  = blockIdx.y * 64;
  const int rbase = (w << 3) + (l >> 3);
  const int kswz  = ((l & 7) ^ (l >> 3)) << 3;
  const u16* pA0 = xb  + (size_t)(b0 + rbase) * IN_DIM + kswz;
  const u16* pB0 = wbt + (size_t)(n0 + rbase) * IN_DIM + kswz;
  u16* ldsA = As + (w << 9);
  u16* ldsB = Bs + (w << 9);
  int aoff[2][2], boff[4][2];
#pragma unroll
  for (int mf = 0; mf < 2; ++mf) {
    const int r = (w << 5) + (mf << 4) + (l & 15);
    const int m = (r & 7) << 4;
#pragma unroll
    for (int kf = 0; kf < 2; ++kf)
      aoff[mf][kf] = (r << 7) + (((kf << 6) + ((l >> 4) << 4)) ^ m);
  }
#pragma unroll
  for (int nf = 0; nf < 4; ++nf) {
    const int r = (nf << 4) + (l & 15);
    const int m = (r & 7) << 4;
#pragma unroll
    for (int kf = 0; kf < 2; ++kf)
      boff[nf][kf] = (r << 7) + (((kf << 6) + ((l >> 4) << 4)) ^ m);
  }
  f32x4 accY[2][4], accE[2][4];
#pragma unroll
  for (int mf = 0; mf < 2; ++mf)
#pragma unroll
    for (int nf = 0; nf < 4; ++nf) {
      accY[mf][nf] = (f32x4){0.f, 0.f, 0.f, 0.f};
      accE[mf][nf] = (f32x4){0.f, 0.f, 0.f, 0.f};
    }
  const char* Asb = (const char*)As;
  const char* Bsb = (const char*)Bs;
  for (int e = 0; e < EXPERTS; ++e) {
    const u16* pA = pA0;
    const u16* pB = pB0 + (size_t)e * IN_DIM * 1024;
    for (int kk = 0; kk < 16; ++kk) {
      const int koff = kk << 6;
      GLDS16(pA + koff,               ldsA);
      GLDS16(pA + koff + 32 * IN_DIM, ldsA + 2048);
      GLDS16(pA + koff + 64 * IN_DIM, ldsA + 4096);
      GLDS16(pA + koff + 96 * IN_DIM, ldsA + 6144);
      GLDS16(pB + koff,               ldsB);
      GLDS16(pB + koff + 32 * IN_DIM, ldsB + 2048);
      __syncthreads();
#pragma unroll
      for (int kf = 0; kf < 2; ++kf) {
        bf16x8 af[2], bfr[4];
#pragma unroll
        for (int mf = 0; mf < 2; ++mf)
          af[mf] = *(const bf16x8*)(Asb + aoff[mf][kf]);
#pragma unroll
        for (int nf = 0; nf < 4; ++nf)
          bfr[nf] = *(const bf16x8*)(Bsb + boff[nf][kf]);
#pragma unroll
        for (int mf = 0; mf < 2; ++mf)
#pragma unroll
          for (int nf = 0; nf < 4; ++nf)
            accE[mf][nf] = MFMA_BF16(af[mf], bfr[nf], accE[mf][nf], 0, 0, 0);
      }
      __syncthreads();
    }
#pragma unroll
    for (int mf = 0; mf < 2; ++mf) {
      const int r0 = b0 + (w << 5) + (mf << 4) + ((l >> 4) << 2);
#pragma unroll
      for (int j = 0; j < 4; ++j) {
        const float we = wts[(size_t)(r0 + j) * EXPERTS + e];
#pragma unroll
        for (int nf = 0; nf < 4; ++nf) {
          accY[mf][nf][j] += we * accE[mf][nf][j];
          accE[mf][nf][j] = 0.f;
        }
      }
    }
  }
#pragma unroll
  for (int mf = 0; mf < 2; ++mf) {
    const int r0 = b0 + (w << 5) + (mf << 4) + ((l >> 4) << 2);
#pragma unroll
    for (int j = 0; j < 4; ++j) {
      const int r = r0 + j;
      const float* wr = wts + (size_t)r * EXPERTS;
      float w8[8];
#pragma unroll
      for (int e2 = 0; e2 < 8; ++e2) w8[e2] = wr[e2];
#pragma unroll
      for (int nf = 0; nf < 4; ++nf) {
        const int c = n0 + (nf << 4) + (l & 15);
        float v = accY[mf][nf][j];
#pragma unroll
        for (int e2 = 0; e2 < 8; ++e2)
          v += w8[e2] * bias[e2 * OUT_DIM + c];
        y[(size_t)r * OUT_DIM + c] = v;
      }
    }
  }
}

extern "C" void kernel_launch(void* const* d_in, const int* in_sizes, int n_in,
                              void* d_out, int out_size, void* d_ws, size_t ws_size,
                              hipStream_t stream) {
  const float* x    = (const float*)d_in[0];
  const float* wts  = (const float*)d_in[1];
  const float* W    = (const float*)d_in[2];
  const float* bias = (const float*)d_in[3];
  float* y = (float*)d_out;

  const size_t Z_ELEMS  = (size_t)BATCH * KS;      // 135,266,304
  const size_t WT_ELEMS = (size_t)OUT_DIM * KS;    //   8,454,144
  if (ws_size >= (Z_ELEMS + WT_ELEMS) * sizeof(u16) + 512) {
    u16* Zb  = (u16*)d_ws;
    u16* Wtb = Zb + Z_ELEMS;
    build_z<<<BATCH, 256, 0, stream>>>(x, wts, Zb);
    build_wt<<<dim3(IN_DIM / 64, OUT_DIM / 64, EXPERTS), 256, 0, stream>>>(W, Wtb);
    bias_tail<<<OUT_DIM / 256, 256, 0, stream>>>(bias, Wtb);
    zgemm<<<dim3((BATCH / 256) * (OUT_DIM / 128)), 512, 0, stream>>>(Zb, Wtb, y);
  } else {
    const size_t xb_elems = (size_t)BATCH * IN_DIM;
    const size_t wb_elems = (size_t)EXPERTS * IN_DIM * OUT_DIM;
    if (ws_size < (xb_elems + wb_elems) * sizeof(u16)) return;
    u16* xb  = (u16*)d_ws;
    u16* wbt = xb + xb_elems;
    cvt_x<<<(BATCH * IN_DIM) / (4 * 256), 256, 0, stream>>>(x, xb);
    cvt_w<<<dim3(IN_DIM / 64, OUT_DIM / 64, EXPERTS), 256, 0, stream>>>(W, wbt);
    moe_gemm<<<dim3(BATCH / 128, OUT_DIM / 64), 256, 0, stream>>>(xb, wbt, wts, bias, y);
  }
}